// Round 1
// baseline (15377.049 us; speedup 1.0000x reference)
//
#include <hip/hip_runtime.h>
#include <math.h>

// Problem constants
#define V_    8000
#define E_    150
#define LD_   50
#define H_    512
#define B_    100
#define T_    50
#define D0_   200   // E_+LD_
#define BT_   5000  // B_*T_
#define NV_   8000  // vocab (N of softmax gemm)

__device__ __forceinline__ float sigmoidf_(float x) { return 1.0f / (1.0f + expf(-x)); }

// ---------------- row L2-normalize: out[r,:] = in[r,:] / sqrt(max(sum sq,1e-12))
__global__ __launch_bounds__(256) void norm_rows(const float* __restrict__ in,
                                                 float* __restrict__ out, int R, int C) {
    int row = blockIdx.x;
    if (row >= R) return;
    int tid = threadIdx.x;
    float v = (tid < C) ? in[(size_t)row * C + tid] : 0.f;
    __shared__ float red[256];
    red[tid] = v * v;
    __syncthreads();
    for (int s = 128; s > 0; s >>= 1) {
        if (tid < s) red[tid] += red[tid + s];
        __syncthreads();
    }
    float scale = rsqrtf(fmaxf(red[0], 1e-12f));
    if (tid < C) out[(size_t)row * C + tid] = v * scale;
}

// ---------------- build xs [T,B,D0] = concat(norm_emb[input[b,t]], norm_lang[langs[b]])
__global__ void build_xs(const int* __restrict__ inp, const int* __restrict__ langs,
                         const float* __restrict__ nemb, const float* __restrict__ nlang,
                         float* __restrict__ xs) {
    int idx = blockIdx.x * 256 + threadIdx.x;
    if (idx >= T_ * B_ * D0_) return;
    int t = idx / (B_ * D0_);
    int rem = idx % (B_ * D0_);
    int b = rem / D0_;
    int e = rem % D0_;
    float v;
    if (e < E_) v = nemb[(size_t)inp[b * T_ + t] * E_ + e];
    else        v = nlang[(size_t)langs[b] * LD_ + (e - E_)];
    xs[idx] = v;
}

// ---------------- generic tiled fp32 GEMM: C[M,N] = A[M,K] @ B[K,N](ldb) + bias
// 64x64 tile, BK=16, 256 threads, 4x4 per thread
__global__ __launch_bounds__(256) void gemm_bias(const float* __restrict__ A,
                                                 const float* __restrict__ Bm,
                                                 const float* __restrict__ bias,
                                                 float* __restrict__ C,
                                                 int M, int N, int K, int ldb) {
    __shared__ __align__(16) float As[16][64];  // [k][m]
    __shared__ __align__(16) float Bs[16][64];  // [k][n]
    const int tid = threadIdx.x;
    const int tx = tid & 15, ty = tid >> 4;
    const int mBase = blockIdx.y * 64, nBase = blockIdx.x * 64;
    float acc[4][4] = {};
    for (int k0 = 0; k0 < K; k0 += 16) {
        int e = tid * 4;
#pragma unroll
        for (int q = 0; q < 4; ++q) {
            int ee = e + q;
            int r = ee >> 4, kk = ee & 15;
            int gr = mBase + r, gk = k0 + kk;
            As[kk][r] = (gr < M && gk < K) ? A[(size_t)gr * K + gk] : 0.f;
        }
        int bk = tid >> 4, bn = (tid & 15) * 4;
        int gk = k0 + bk;
        float4 bv = make_float4(0.f, 0.f, 0.f, 0.f);
        if (gk < K) bv = *(const float4*)(Bm + (size_t)gk * ldb + nBase + bn);
        *(float4*)&Bs[bk][bn] = bv;
        __syncthreads();
#pragma unroll
        for (int kk = 0; kk < 16; ++kk) {
            const float4 a4 = *(const float4*)&As[kk][ty * 4];
            const float4 b4 = *(const float4*)&Bs[kk][tx * 4];
            float a[4] = {a4.x, a4.y, a4.z, a4.w};
            float b[4] = {b4.x, b4.y, b4.z, b4.w};
#pragma unroll
            for (int i = 0; i < 4; ++i)
#pragma unroll
                for (int j = 0; j < 4; ++j) acc[i][j] += a[i] * b[j];
        }
        __syncthreads();
    }
#pragma unroll
    for (int i = 0; i < 4; ++i) {
        int gr = mBase + ty * 4 + i;
        if (gr < M) {
#pragma unroll
            for (int j = 0; j < 4; ++j) {
                int gc = nBase + tx * 4 + j;
                if (gc < N) C[(size_t)gr * N + gc] = acc[i][j] + (bias ? bias[gc] : 0.f);
            }
        }
    }
}

// ---------------- persistent GRU recurrence: 25 blocks x 4 batch rows, whole T loop
// Layer0: gates use precomputed Xg0 (= xs@Wg0_x + bg0); cand uses Xc0.
// Layer1: full [h0,h1]@Wg1 + bg1 etc. computed live.
// h1 outputs written in [B*T, H] layout (row = b*T + t) for the softmax GEMM.
__global__ __launch_bounds__(1024) void rnn_kernel(
    const float* __restrict__ Xg0, const float* __restrict__ Xc0,
    const float* __restrict__ Wg0h, const float* __restrict__ Wc0h,
    const float* __restrict__ Wg1, const float* __restrict__ bg1,
    const float* __restrict__ Wc1, const float* __restrict__ bc1,
    float* __restrict__ h1o) {
    __shared__ float h0s[4][512];
    __shared__ float h1s[4][512];
    __shared__ float rhs[4][512];
    __shared__ float uus[4][512];
    const int tid = threadIdx.x;
    const int r0 = blockIdx.x * 4;
    for (int i = tid; i < 4 * 512; i += 1024) {
        ((float*)h0s)[i] = 0.f;
        ((float*)h1s)[i] = 0.f;
    }
    __syncthreads();
    for (int t = 0; t < T_; ++t) {
        {  // phase A: layer0 gates, col = tid (0..1023), 4 rows
            const int col = tid;
            const float* xg = Xg0 + ((size_t)t * B_ + r0) * 1024 + col;
            float a0 = xg[0], a1 = xg[1024], a2 = xg[2048], a3 = xg[3072];
#pragma unroll 4
            for (int k = 0; k < 512; ++k) {
                float wv = Wg0h[(size_t)k * 1024 + col];
                a0 += h0s[0][k] * wv; a1 += h0s[1][k] * wv;
                a2 += h0s[2][k] * wv; a3 += h0s[3][k] * wv;
            }
            float s0 = sigmoidf_(a0), s1 = sigmoidf_(a1), s2 = sigmoidf_(a2), s3 = sigmoidf_(a3);
            if (col < 512) {
                rhs[0][col] = s0 * h0s[0][col]; rhs[1][col] = s1 * h0s[1][col];
                rhs[2][col] = s2 * h0s[2][col]; rhs[3][col] = s3 * h0s[3][col];
            } else {
                int c2 = col - 512;
                uus[0][c2] = s0; uus[1][c2] = s1; uus[2][c2] = s2; uus[3][c2] = s3;
            }
        }
        __syncthreads();
        {  // phase B: layer0 candidate + h0 update; 2 (row,col) pairs per thread
            const int half = tid >> 9, col = tid & 511;
            float hn[2];
#pragma unroll
            for (int q = 0; q < 2; ++q) {
                int rr = half + q * 2;
                float acc = Xc0[((size_t)t * B_ + r0 + rr) * 512 + col];
#pragma unroll 4
                for (int k = 0; k < 512; ++k) acc += rhs[rr][k] * Wc0h[(size_t)k * 512 + col];
                float c = tanhf(acc);
                float u = uus[rr][col];
                hn[q] = u * h0s[rr][col] + (1.f - u) * c;
            }
            __syncthreads();
            h0s[half][col] = hn[0];
            h0s[half + 2][col] = hn[1];
        }
        __syncthreads();
        {  // phase C: layer1 gates (x-part = h0, h-part = h1)
            const int col = tid;
            float a0 = bg1[col];
            float a1 = a0, a2 = a0, a3 = a0;
#pragma unroll 4
            for (int k = 0; k < 512; ++k) {
                float wv = Wg1[(size_t)k * 1024 + col];
                a0 += h0s[0][k] * wv; a1 += h0s[1][k] * wv;
                a2 += h0s[2][k] * wv; a3 += h0s[3][k] * wv;
            }
#pragma unroll 4
            for (int k = 0; k < 512; ++k) {
                float wv = Wg1[(size_t)(512 + k) * 1024 + col];
                a0 += h1s[0][k] * wv; a1 += h1s[1][k] * wv;
                a2 += h1s[2][k] * wv; a3 += h1s[3][k] * wv;
            }
            float s0 = sigmoidf_(a0), s1 = sigmoidf_(a1), s2 = sigmoidf_(a2), s3 = sigmoidf_(a3);
            if (col < 512) {
                rhs[0][col] = s0 * h1s[0][col]; rhs[1][col] = s1 * h1s[1][col];
                rhs[2][col] = s2 * h1s[2][col]; rhs[3][col] = s3 * h1s[3][col];
            } else {
                int c2 = col - 512;
                uus[0][c2] = s0; uus[1][c2] = s1; uus[2][c2] = s2; uus[3][c2] = s3;
            }
        }
        __syncthreads();
        {  // phase D: layer1 candidate + h1 update + output store
            const int half = tid >> 9, col = tid & 511;
            float hn[2];
#pragma unroll
            for (int q = 0; q < 2; ++q) {
                int rr = half + q * 2;
                float acc = bc1[col];
#pragma unroll 4
                for (int k = 0; k < 512; ++k) acc += h0s[rr][k] * Wc1[(size_t)k * 512 + col];
#pragma unroll 4
                for (int k = 0; k < 512; ++k) acc += rhs[rr][k] * Wc1[(size_t)(512 + k) * 512 + col];
                float c = tanhf(acc);
                float u = uus[rr][col];
                hn[q] = u * h1s[rr][col] + (1.f - u) * c;
            }
            __syncthreads();
            h1s[half][col] = hn[0];
            h1s[half + 2][col] = hn[1];
            h1o[((size_t)(r0 + half) * T_ + t) * 512 + col] = hn[0];
            h1o[((size_t)(r0 + half + 2) * T_ + t) * 512 + col] = hn[1];
        }
        __syncthreads();
    }
}

// ---------------- target logit: zt[i] = h1o[i,:] . sw[:, tgt[i]] + sb[tgt[i]]
__global__ __launch_bounds__(256) void target_logit(const float* __restrict__ h1o,
                                                    const float* __restrict__ sw,
                                                    const float* __restrict__ sb,
                                                    const int* __restrict__ tgt,
                                                    float* __restrict__ zt) {
    int row = blockIdx.x * 4 + (threadIdx.x >> 6);
    int lane = threadIdx.x & 63;
    if (row >= BT_) return;
    int tg = tgt[row];
    float p = 0.f;
    for (int k = lane; k < 512; k += 64) p += h1o[(size_t)row * 512 + k] * sw[(size_t)k * NV_ + tg];
    for (int off = 32; off > 0; off >>= 1) p += __shfl_down(p, off);
    if (lane == 0) zt[row] = p + sb[tg];
}

// ---------------- fused softmax GEMM + per-tile online-LSE partials
// logits tile = h1o[64 rows, 512] @ sw[512, 64 cols] + sb; emits (rowmax, sumexp) per (row, coltile)
__global__ __launch_bounds__(256) void lse_gemm(const float* __restrict__ A,
                                                const float* __restrict__ Bw,
                                                const float* __restrict__ bias,
                                                float* __restrict__ parts, int M) {
    __shared__ __align__(16) float As[16][64];
    __shared__ __align__(16) float Bs[16][64];
    __shared__ float red[64][17];
    __shared__ float rowm[64];
    const int tid = threadIdx.x;
    const int tx = tid & 15, ty = tid >> 4;
    const int mBase = blockIdx.y * 64, nBase = blockIdx.x * 64;
    float acc[4][4] = {};
    for (int k0 = 0; k0 < 512; k0 += 16) {
        // A: float4 along k
        int r = tid >> 2;
        int ak = (tid & 3) * 4;
        float4 av = make_float4(0.f, 0.f, 0.f, 0.f);
        if (mBase + r < M) av = *(const float4*)(A + (size_t)(mBase + r) * 512 + k0 + ak);
        As[ak][r] = av.x; As[ak + 1][r] = av.y; As[ak + 2][r] = av.z; As[ak + 3][r] = av.w;
        int bk = tid >> 4, bn = (tid & 15) * 4;
        float4 bv = *(const float4*)(Bw + (size_t)(k0 + bk) * NV_ + nBase + bn);
        *(float4*)&Bs[bk][bn] = bv;
        __syncthreads();
#pragma unroll
        for (int kk = 0; kk < 16; ++kk) {
            const float4 a4 = *(const float4*)&As[kk][ty * 4];
            const float4 b4 = *(const float4*)&Bs[kk][tx * 4];
            float a[4] = {a4.x, a4.y, a4.z, a4.w};
            float b[4] = {b4.x, b4.y, b4.z, b4.w};
#pragma unroll
            for (int i = 0; i < 4; ++i)
#pragma unroll
                for (int j = 0; j < 4; ++j) acc[i][j] += a[i] * b[j];
        }
        __syncthreads();
    }
    // add bias (softmax_b)
#pragma unroll
    for (int j = 0; j < 4; ++j) {
        float bb = bias[nBase + tx * 4 + j];
#pragma unroll
        for (int i = 0; i < 4; ++i) acc[i][j] += bb;
    }
    // per-row max over this 64-col tile
#pragma unroll
    for (int i = 0; i < 4; ++i) {
        float lm = fmaxf(fmaxf(acc[i][0], acc[i][1]), fmaxf(acc[i][2], acc[i][3]));
        red[ty * 4 + i][tx] = lm;
    }
    __syncthreads();
    if (tid < 64) {
        float m = red[tid][0];
#pragma unroll
        for (int c = 1; c < 16; ++c) m = fmaxf(m, red[tid][c]);
        rowm[tid] = m;
    }
    __syncthreads();
#pragma unroll
    for (int i = 0; i < 4; ++i) {
        float m = rowm[ty * 4 + i];
        float ls = expf(acc[i][0] - m) + expf(acc[i][1] - m) + expf(acc[i][2] - m) + expf(acc[i][3] - m);
        red[ty * 4 + i][tx] = ls;
    }
    __syncthreads();
    if (tid < 64) {
        float s = 0.f;
#pragma unroll
        for (int c = 0; c < 16; ++c) s += red[tid][c];
        int gr = mBase + tid;
        if (gr < M) {
            parts[(size_t)gr * 250 + blockIdx.x * 2 + 0] = rowm[tid];
            parts[(size_t)gr * 250 + blockIdx.x * 2 + 1] = s;
        }
    }
}

// ---------------- merge partials -> per-row NLL -> per-block sum
__global__ __launch_bounds__(128) void final_nll(const float* __restrict__ parts,
                                                 const float* __restrict__ zt,
                                                 float* __restrict__ bsum) {
    int i = blockIdx.x * 128 + threadIdx.x;
    float nll = 0.f;
    if (i < BT_) {
        const float* p = parts + (size_t)i * 250;
        float M = p[0];
        for (int j = 1; j < 125; ++j) M = fmaxf(M, p[2 * j]);
        float S = 0.f;
        for (int j = 0; j < 125; ++j) S += p[2 * j + 1] * expf(p[2 * j] - M);
        nll = M + logf(S) - zt[i];
    }
    __shared__ float red[128];
    red[threadIdx.x] = nll;
    __syncthreads();
    for (int s = 64; s > 0; s >>= 1) {
        if (threadIdx.x < s) red[threadIdx.x] += red[threadIdx.x + s];
        __syncthreads();
    }
    if (threadIdx.x == 0) bsum[blockIdx.x] = red[0];
}

__global__ __launch_bounds__(64) void final_sum(const float* __restrict__ bsum,
                                                float* __restrict__ out) {
    int tid = threadIdx.x;
    float v = (tid < 40) ? bsum[tid] : 0.f;
    for (int off = 32; off > 0; off >>= 1) v += __shfl_down(v, off);
    if (tid == 0) out[0] = v / 5000.0f;
}

extern "C" void kernel_launch(void* const* d_in, const int* in_sizes, int n_in,
                              void* d_out, int out_size, void* d_ws, size_t ws_size,
                              hipStream_t stream) {
    const int*   inp   = (const int*)d_in[0];
    const int*   langs = (const int*)d_in[1];
    const int*   tgt   = (const int*)d_in[2];
    const float* emb   = (const float*)d_in[3];
    const float* lemb  = (const float*)d_in[4];
    const float* Wg0   = (const float*)d_in[5];
    const float* bg0   = (const float*)d_in[6];
    const float* Wc0   = (const float*)d_in[7];
    const float* bc0   = (const float*)d_in[8];
    const float* Wg1   = (const float*)d_in[9];
    const float* bg1   = (const float*)d_in[10];
    const float* Wc1   = (const float*)d_in[11];
    const float* bc1   = (const float*)d_in[12];
    const float* sw    = (const float*)d_in[13];
    const float* sb    = (const float*)d_in[14];
    float* out = (float*)d_out;

    // workspace layout (floats). parts aliases the nemb/nlang/xs region (dead by then).
    float* w     = (float*)d_ws;
    float* nemb  = w;                    // 1,200,000
    float* nlang = w + 1200000;          // 512
    float* xs    = w + 1200512;          // 1,000,000  (ends 2,200,512)
    float* parts = w;                    // 1,250,000  (alias; used after xs is dead)
    float* Xg0   = w + 2200512;          // 5,120,000
    float* Xc0   = Xg0 + 5120000;        // 2,560,000
    float* h1o   = Xc0 + 2560000;        // 2,560,000
    float* ztb   = h1o + 2560000;        // 5,120
    float* bsum  = ztb + 5120;           // 64
    // total ~12.45M floats ~= 50 MB

    norm_rows<<<V_, 256, 0, stream>>>(emb, nemb, V_, E_);
    norm_rows<<<10, 256, 0, stream>>>(lemb, nlang, 10, LD_);
    build_xs<<<(T_ * B_ * D0_ + 255) / 256, 256, 0, stream>>>(inp, langs, nemb, nlang, xs);
    gemm_bias<<<dim3(16, 79), 256, 0, stream>>>(xs, Wg0, bg0, Xg0, BT_, 1024, D0_, 1024);
    gemm_bias<<<dim3(8, 79), 256, 0, stream>>>(xs, Wc0, bc0, Xc0, BT_, 512, D0_, 512);
    rnn_kernel<<<25, 1024, 0, stream>>>(Xg0, Xc0, Wg0 + 200 * 1024, Wc0 + 200 * 512,
                                        Wg1, bg1, Wc1, bc1, h1o);
    target_logit<<<1250, 256, 0, stream>>>(h1o, sw, sb, tgt, ztb);
    lse_gemm<<<dim3(125, 79), 256, 0, stream>>>(h1o, sw, sb, parts, BT_);
    final_nll<<<40, 128, 0, stream>>>(parts, ztb, bsum);
    final_sum<<<1, 64, 0, stream>>>(bsum, out);
}

// Round 2
// 14105.717 us; speedup vs baseline: 1.0901x; 1.0901x over previous
//
#include <hip/hip_runtime.h>
#include <math.h>

// Problem constants
#define V_    8000
#define E_    150
#define LD_   50
#define H_    512
#define B_    100
#define T_    50
#define D0_   200   // E_+LD_
#define BT_   5000  // B_*T_
#define NV_   8000
#define MP_   5120  // padded BT (column dim of transposed activations)
#define RP_   128   // padded batch rows
#define NBLK_ 128   // rnn persistent blocks

__device__ __forceinline__ float sigmoidf_(float x) { return 1.0f / (1.0f + __expf(-x)); }

// ---------------- row L2-normalize
__global__ __launch_bounds__(256) void norm_rows(const float* __restrict__ in,
                                                 float* __restrict__ out, int R, int C) {
    int row = blockIdx.x;
    if (row >= R) return;
    int tid = threadIdx.x;
    float v = (tid < C) ? in[(size_t)row * C + tid] : 0.f;
    __shared__ float red[256];
    red[tid] = v * v;
    __syncthreads();
    for (int s = 128; s > 0; s >>= 1) {
        if (tid < s) red[tid] += red[tid + s];
        __syncthreads();
    }
    float scale = rsqrtf(fmaxf(red[0], 1e-12f));
    if (tid < C) out[(size_t)row * C + tid] = v * scale;
}

// ---------------- build xsT [D0][MP_]: xsT[e][t*100+b] = concat(emb, lang)
__global__ void build_xsT(const int* __restrict__ inp, const int* __restrict__ langs,
                          const float* __restrict__ nemb, const float* __restrict__ nlang,
                          float* __restrict__ xsT) {
    int idx = blockIdx.x * 256 + threadIdx.x;
    if (idx >= D0_ * BT_) return;
    int e = idx / BT_, m = idx % BT_;
    int t = m / 100, b = m % 100;
    float v = (e < E_) ? nemb[(size_t)inp[b * T_ + t] * E_ + e]
                       : nlang[(size_t)langs[b] * LD_ + (e - E_)];
    xsT[(size_t)e * MP_ + m] = v;
}

// ---------------- C[M][MP_] = At^T(stored [K=200][lda]) @ B[K][MP_] + bias[row]
// M = 1024 or 512 (grid.y*64), N = 5120 (grid.x*64)
__global__ __launch_bounds__(256) void gemm_at_bias(const float* __restrict__ At,
                                                    const float* __restrict__ Bm,
                                                    const float* __restrict__ bias,
                                                    float* __restrict__ C, int lda) {
    __shared__ __align__(16) float As[16][64];
    __shared__ __align__(16) float Bs[16][64];
    const int tid = threadIdx.x;
    const int tx = tid & 15, ty = tid >> 4;
    const int mBase = blockIdx.y * 64, nBase = blockIdx.x * 64;
    float acc[4][4] = {};
    for (int k0 = 0; k0 < 208; k0 += 16) {
        int kk = tid >> 4, c4 = (tid & 15) * 4;
        int gk = k0 + kk;
        float4 av = make_float4(0.f, 0.f, 0.f, 0.f);
        float4 bv = make_float4(0.f, 0.f, 0.f, 0.f);
        if (gk < 200) {
            av = *(const float4*)(At + (size_t)gk * lda + mBase + c4);
            bv = *(const float4*)(Bm + (size_t)gk * MP_ + nBase + c4);
        }
        *(float4*)&As[kk][c4] = av;
        *(float4*)&Bs[kk][c4] = bv;
        __syncthreads();
#pragma unroll
        for (int k = 0; k < 16; ++k) {
            const float4 a4 = *(const float4*)&As[k][ty * 4];
            const float4 b4 = *(const float4*)&Bs[k][tx * 4];
            float a[4] = {a4.x, a4.y, a4.z, a4.w};
            float b[4] = {b4.x, b4.y, b4.z, b4.w};
#pragma unroll
            for (int i = 0; i < 4; ++i)
#pragma unroll
                for (int j = 0; j < 4; ++j) acc[i][j] += a[i] * b[j];
        }
        __syncthreads();
    }
#pragma unroll
    for (int i = 0; i < 4; ++i) {
        int gr = mBase + ty * 4 + i;
        float bb = bias[gr];
#pragma unroll
        for (int j = 0; j < 4; ++j) C[(size_t)gr * MP_ + nBase + tx * 4 + j] = acc[i][j] + bb;
    }
}

// ---------------- persistent RNN: 128 blocks x 256 threads, software grid barrier
// State transposed: hT[k][RP_]. Each block owns gate cols [bid*8,+8) and cand cols [bid*4,+4).
// Weight slices preloaded in LDS (survive the L2 invalidations from fences).

__device__ __forceinline__ void gbar(unsigned* bar, unsigned btarget, int tid) {
    __syncthreads();
    if (tid == 0) {
        __threadfence();
        __hip_atomic_fetch_add(bar, 1u, __ATOMIC_ACQ_REL, __HIP_MEMORY_SCOPE_AGENT);
        while (__hip_atomic_load(bar, __ATOMIC_ACQUIRE, __HIP_MEMORY_SCOPE_AGENT) < btarget)
            __builtin_amdgcn_s_sleep(2);
        __threadfence();
    }
    __syncthreads();
}

// one GEMM phase: acc[NCOL] += sum_k hsrc[k][row] * Wlds[k][cg*NCOL + j]
// K = NCHUNK*64; chunks 0..7 from src0, 8..15 from src1. 2-deep prefetch pipeline.
template<int NCHUNK, int NCOL>
__device__ __forceinline__ void phase_mm(const float* __restrict__ src0,
                                         const float* __restrict__ src1,
                                         const float* __restrict__ wl,
                                         float* __restrict__ hb,
                                         int tid, int row, int cg,
                                         float* __restrict__ acc) {
    const float* wt = wl + cg * NCOL;
    float4 stA[8], stB[8];
#define CPTR_(c) ((c) < 8 ? (src0 + (size_t)(c) * 8192) : (src1 + (size_t)((c) - 8) * 8192))
    {   // chunk 0 -> LDS buf 0
        const float* s = CPTR_(0);
#pragma unroll
        for (int q = 0; q < 8; ++q) stA[q] = *(const float4*)(s + q * 1024 + tid * 4);
#pragma unroll
        for (int q = 0; q < 8; ++q) *(float4*)(hb + q * 1024 + tid * 4) = stA[q];
    }
    if (NCHUNK > 1) {  // chunk 1 -> stA
        const float* s = CPTR_(1);
#pragma unroll
        for (int q = 0; q < 8; ++q) stA[q] = *(const float4*)(s + q * 1024 + tid * 4);
    }
    if (NCHUNK > 2) {  // chunk 2 -> stB
        const float* s = CPTR_(2);
#pragma unroll
        for (int q = 0; q < 8; ++q) stB[q] = *(const float4*)(s + q * 1024 + tid * 4);
    }
    __syncthreads();
#define PH_ITER_(ci, stc) \
    if ((ci) < NCHUNK) { \
        if ((ci) + 1 < NCHUNK) { \
            float* dst = hb + (((ci) + 1) & 1) * 8192; \
            _Pragma("unroll") \
            for (int q = 0; q < 8; ++q) *(float4*)(dst + q * 1024 + tid * 4) = stc[q]; \
            if ((ci) + 3 < NCHUNK) { \
                const float* s = CPTR_((ci) + 3); \
                _Pragma("unroll") \
                for (int q = 0; q < 8; ++q) stc[q] = *(const float4*)(s + q * 1024 + tid * 4); \
            } \
        } \
        const float* hc = hb + ((ci) & 1) * 8192; \
        const float* wrow = wt + (size_t)(ci) * 64 * (2 * NCOL); \
        _Pragma("unroll 8") \
        for (int kk = 0; kk < 64; ++kk) { \
            float h = hc[kk * RP_ + row]; \
            if (NCOL == 4) { \
                float4 wv = *(const float4*)(wrow + (size_t)kk * 8); \
                acc[0] = fmaf(h, wv.x, acc[0]); acc[1] = fmaf(h, wv.y, acc[1]); \
                acc[2] = fmaf(h, wv.z, acc[2]); acc[3] = fmaf(h, wv.w, acc[3]); \
            } else { \
                float2 wv = *(const float2*)(wrow + (size_t)kk * 4); \
                acc[0] = fmaf(h, wv.x, acc[0]); acc[1] = fmaf(h, wv.y, acc[1]); \
            } \
        } \
        __syncthreads(); \
    }
    for (int cb = 0; cb < NCHUNK; cb += 2) {
        PH_ITER_(cb, stA);
        PH_ITER_(cb + 1, stB);
    }
#undef PH_ITER_
#undef CPTR_
}

__global__ __launch_bounds__(256) void rnn_persistent(
    const float* __restrict__ Xg0T, const float* __restrict__ Xc0T,
    const float* __restrict__ Wg0, const float* __restrict__ Wc0,
    const float* __restrict__ Wg1, const float* __restrict__ bg1,
    const float* __restrict__ Wc1, const float* __restrict__ bc1,
    float* __restrict__ h0T, float* __restrict__ h1T,
    float* __restrict__ rh0T, float* __restrict__ u0T,
    float* __restrict__ rh1T, float* __restrict__ u1T,
    float* __restrict__ h1oT, unsigned* __restrict__ bar) {
    __shared__ __align__(16) float hb[16384];    // 64KB: double-buffered 64x128 chunk
    __shared__ __align__(16) float wg0s[4096];   // [512][8]
    __shared__ __align__(16) float wg1s[8192];   // [1024][8]
    __shared__ __align__(16) float wc0s[2048];   // [512][4]
    __shared__ __align__(16) float wc1s[4096];   // [1024][4]
    const int tid = threadIdx.x;
    const int bid = blockIdx.x;
    const int row = tid & 127;
    const int cg = tid >> 7;              // 0/1
    const int gc0 = bid * 8 + cg * 4;     // gate col base (phases A,C): 4 cols
    const int cc0 = bid * 4 + cg * 2;     // cand col base (phases B,D): 2 cols

    // ---- preload weight slices to LDS (once; read-only, fence-immune)
    for (int i = tid; i < 4096; i += 256) {
        int k = i >> 3, c = i & 7;
        wg0s[i] = Wg0[(size_t)(D0_ + k) * 1024 + bid * 8 + c];
    }
    for (int i = tid; i < 8192; i += 256) {
        int k = i >> 3, c = i & 7;
        wg1s[i] = Wg1[(size_t)k * 1024 + bid * 8 + c];
    }
    for (int i = tid; i < 2048; i += 256) {
        int k = i >> 2, c = i & 3;
        wc0s[i] = Wc0[(size_t)(D0_ + k) * 512 + bid * 4 + c];
    }
    for (int i = tid; i < 4096; i += 256) {
        int k = i >> 2, c = i & 3;
        wc1s[i] = Wc1[(size_t)k * 512 + bid * 4 + c];
    }
    float bg1v0 = bg1[gc0], bg1v1 = bg1[gc0 + 1], bg1v2 = bg1[gc0 + 2], bg1v3 = bg1[gc0 + 3];
    float bc1v0 = bc1[cc0], bc1v1 = bc1[cc0 + 1];
    __syncthreads();

    unsigned btarget = 0;
    for (int t = 0; t < T_; ++t) {
        {   // ---- phase A: gates0 = sigmoid(Xg0 + h0 @ Wg0h); write rh0 / u0
            float acc[4];
            const float* xg = Xg0T + (size_t)gc0 * MP_ + t * 100 + row;
            acc[0] = xg[0]; acc[1] = xg[MP_]; acc[2] = xg[2 * MP_]; acc[3] = xg[3 * MP_];
            phase_mm<8, 4>(h0T, nullptr, wg0s, hb, tid, row, cg, acc);
            if (gc0 < 512) {
#pragma unroll
                for (int j = 0; j < 4; ++j) {
                    float r = sigmoidf_(acc[j]);
                    rh0T[(gc0 + j) * RP_ + row] = r * h0T[(gc0 + j) * RP_ + row];
                }
            } else {
#pragma unroll
                for (int j = 0; j < 4; ++j)
                    u0T[(gc0 - 512 + j) * RP_ + row] = sigmoidf_(acc[j]);
            }
        }
        btarget += NBLK_; gbar(bar, btarget, tid);
        {   // ---- phase B: h0 = u*h0 + (1-u)*tanh(Xc0 + rh0 @ Wc0h)
            float acc[2];
            const float* xc = Xc0T + (size_t)cc0 * MP_ + t * 100 + row;
            acc[0] = xc[0]; acc[1] = xc[MP_];
            phase_mm<8, 2>(rh0T, nullptr, wc0s, hb, tid, row, cg, acc);
#pragma unroll
            for (int j = 0; j < 2; ++j) {
                float c = tanhf(acc[j]);
                float u = u0T[(cc0 + j) * RP_ + row];
                float ho = h0T[(cc0 + j) * RP_ + row];
                h0T[(cc0 + j) * RP_ + row] = u * ho + (1.f - u) * c;
            }
        }
        btarget += NBLK_; gbar(bar, btarget, tid);
        {   // ---- phase C: gates1 = sigmoid(bg1 + h0@Wg1[:512] + h1@Wg1[512:])
            float acc[4] = {bg1v0, bg1v1, bg1v2, bg1v3};
            phase_mm<16, 4>(h0T, h1T, wg1s, hb, tid, row, cg, acc);
            if (gc0 < 512) {
#pragma unroll
                for (int j = 0; j < 4; ++j) {
                    float r = sigmoidf_(acc[j]);
                    rh1T[(gc0 + j) * RP_ + row] = r * h1T[(gc0 + j) * RP_ + row];
                }
            } else {
#pragma unroll
                for (int j = 0; j < 4; ++j)
                    u1T[(gc0 - 512 + j) * RP_ + row] = sigmoidf_(acc[j]);
            }
        }
        btarget += NBLK_; gbar(bar, btarget, tid);
        {   // ---- phase D: h1 = u1*h1 + (1-u1)*tanh(bc1 + h0@Wc1[:512] + rh1@Wc1[512:])
            float acc[2] = {bc1v0, bc1v1};
            phase_mm<16, 2>(h0T, rh1T, wc1s, hb, tid, row, cg, acc);
#pragma unroll
            for (int j = 0; j < 2; ++j) {
                float c = tanhf(acc[j]);
                float u = u1T[(cc0 + j) * RP_ + row];
                float h1old = h1T[(cc0 + j) * RP_ + row];
                float hn = u * h1old + (1.f - u) * c;
                h1T[(cc0 + j) * RP_ + row] = hn;
                if (row < 100) h1oT[(size_t)(cc0 + j) * MP_ + t * 100 + row] = hn;
            }
        }
        // no barrier needed between D and next A (disjoint read/write sets);
        // next A's bar covers D->C(next) dependencies.
    }
}

// ---------------- fused softmax GEMM + per-tile LSE partials + target-logit pick
// A = h1oT [512][MP_] (transposed), B = sw [512][8000]
__global__ __launch_bounds__(256) void lse_gemm(const float* __restrict__ A,
                                                const float* __restrict__ Bw,
                                                const float* __restrict__ bias,
                                                const int* __restrict__ tgt,
                                                float* __restrict__ zt,
                                                float* __restrict__ parts) {
    __shared__ __align__(16) float As[16][64];
    __shared__ __align__(16) float Bs[16][64];
    __shared__ float red[64][17];
    __shared__ float rowm[64];
    const int tid = threadIdx.x;
    const int tx = tid & 15, ty = tid >> 4;
    const int mBase = blockIdx.y * 64, nBase = blockIdx.x * 64;
    float acc[4][4] = {};
    for (int k0 = 0; k0 < 512; k0 += 16) {
        int kk = tid >> 4, c4 = (tid & 15) * 4;
        float4 av = *(const float4*)(A + (size_t)(k0 + kk) * MP_ + mBase + c4);
        *(float4*)&As[kk][c4] = av;
        float4 bv = *(const float4*)(Bw + (size_t)(k0 + kk) * NV_ + nBase + c4);
        *(float4*)&Bs[kk][c4] = bv;
        __syncthreads();
#pragma unroll
        for (int k = 0; k < 16; ++k) {
            const float4 a4 = *(const float4*)&As[k][ty * 4];
            const float4 b4 = *(const float4*)&Bs[k][tx * 4];
            float a[4] = {a4.x, a4.y, a4.z, a4.w};
            float b[4] = {b4.x, b4.y, b4.z, b4.w};
#pragma unroll
            for (int i = 0; i < 4; ++i)
#pragma unroll
                for (int j = 0; j < 4; ++j) acc[i][j] += a[i] * b[j];
        }
        __syncthreads();
    }
#pragma unroll
    for (int j = 0; j < 4; ++j) {
        float bb = bias[nBase + tx * 4 + j];
#pragma unroll
        for (int i = 0; i < 4; ++i) acc[i][j] += bb;
    }
    // target logit pick (row m -> targets index (m%100)*50 + m/100)
#pragma unroll
    for (int i = 0; i < 4; ++i) {
        int gr = mBase + ty * 4 + i;
        if (gr < BT_) {
            int tg = tgt[(gr % 100) * 50 + gr / 100];
            int lj = tg - nBase - tx * 4;
            if (lj == 0) zt[gr] = acc[i][0];
            else if (lj == 1) zt[gr] = acc[i][1];
            else if (lj == 2) zt[gr] = acc[i][2];
            else if (lj == 3) zt[gr] = acc[i][3];
        }
    }
    // per-row max over this 64-col tile
#pragma unroll
    for (int i = 0; i < 4; ++i) {
        float lm = fmaxf(fmaxf(acc[i][0], acc[i][1]), fmaxf(acc[i][2], acc[i][3]));
        red[ty * 4 + i][tx] = lm;
    }
    __syncthreads();
    if (tid < 64) {
        float m = red[tid][0];
#pragma unroll
        for (int c = 1; c < 16; ++c) m = fmaxf(m, red[tid][c]);
        rowm[tid] = m;
    }
    __syncthreads();
#pragma unroll
    for (int i = 0; i < 4; ++i) {
        float m = rowm[ty * 4 + i];
        float ls = expf(acc[i][0] - m) + expf(acc[i][1] - m) + expf(acc[i][2] - m) + expf(acc[i][3] - m);
        red[ty * 4 + i][tx] = ls;
    }
    __syncthreads();
    if (tid < 64) {
        float s = 0.f;
#pragma unroll
        for (int c = 0; c < 16; ++c) s += red[tid][c];
        int gr = mBase + tid;
        if (gr < BT_) {
            parts[(size_t)gr * 250 + blockIdx.x * 2 + 0] = rowm[tid];
            parts[(size_t)gr * 250 + blockIdx.x * 2 + 1] = s;
        }
    }
}

// ---------------- merge partials -> NLL -> block sums
__global__ __launch_bounds__(128) void final_nll(const float* __restrict__ parts,
                                                 const float* __restrict__ zt,
                                                 float* __restrict__ bsum) {
    int i = blockIdx.x * 128 + threadIdx.x;
    float nll = 0.f;
    if (i < BT_) {
        const float* p = parts + (size_t)i * 250;
        float M = p[0];
        for (int j = 1; j < 125; ++j) M = fmaxf(M, p[2 * j]);
        float S = 0.f;
        for (int j = 0; j < 125; ++j) S += p[2 * j + 1] * expf(p[2 * j] - M);
        nll = M + logf(S) - zt[i];
    }
    __shared__ float red[128];
    red[threadIdx.x] = nll;
    __syncthreads();
    for (int s = 64; s > 0; s >>= 1) {
        if (threadIdx.x < s) red[threadIdx.x] += red[threadIdx.x + s];
        __syncthreads();
    }
    if (threadIdx.x == 0) bsum[blockIdx.x] = red[0];
}

__global__ __launch_bounds__(64) void final_sum(const float* __restrict__ bsum,
                                                float* __restrict__ out) {
    int tid = threadIdx.x;
    float v = (tid < 40) ? bsum[tid] : 0.f;
    for (int off = 32; off > 0; off >>= 1) v += __shfl_down(v, off);
    if (tid == 0) out[0] = v / 5000.0f;
}

extern "C" void kernel_launch(void* const* d_in, const int* in_sizes, int n_in,
                              void* d_out, int out_size, void* d_ws, size_t ws_size,
                              hipStream_t stream) {
    const int*   inp   = (const int*)d_in[0];
    const int*   langs = (const int*)d_in[1];
    const int*   tgt   = (const int*)d_in[2];
    const float* emb   = (const float*)d_in[3];
    const float* lemb  = (const float*)d_in[4];
    const float* Wg0   = (const float*)d_in[5];
    const float* bg0   = (const float*)d_in[6];
    const float* Wc0   = (const float*)d_in[7];
    const float* bc0   = (const float*)d_in[8];
    const float* Wg1   = (const float*)d_in[9];
    const float* bg1   = (const float*)d_in[10];
    const float* Wc1   = (const float*)d_in[11];
    const float* bc1   = (const float*)d_in[12];
    const float* sw    = (const float*)d_in[13];
    const float* sb    = (const float*)d_in[14];
    float* out = (float*)d_out;

    // workspace layout (floats), total ~10.88M floats = 43.5 MB
    float* w = (float*)d_ws;
    // region A (0 .. 2,621,440): nemb+nlang+xsT, later aliased by h1oT
    float* nemb  = w;                       // 1,200,000
    float* nlang = w + 1200000;             // 500 (pad to 512)
    float* xsT   = w + 1200512;             // 200*5120 = 1,024,000
    float* h1oT  = w;                       // 512*5120 = 2,621,440 (alias, after xsT dead)
    // region B (2,621,440 ..): Xg0T, later aliased by parts/zt/bsum
    float* Xg0T  = w + 2621440;             // 1024*5120 = 5,242,880
    float* parts = w + 2621440;             // 5000*250 = 1,250,000 (alias)
    float* ztb   = w + 2621440 + 1250000;   // 5,000
    float* bsum  = w + 2621440 + 1255000;   // 64
    // region C
    float* Xc0T  = w + 7864320;             // 512*5120 = 2,621,440
    // region D: transposed state
    float* h0T   = w + 10485760;            // 512*128 = 65,536
    float* h1T   = w + 10551296;            // 65,536
    float* rh0T  = w + 10616832;            // 65,536
    float* u0T   = w + 10682368;            // 65,536
    float* rh1T  = w + 10747904;            // 65,536
    float* u1T   = w + 10813440;            // 65,536
    unsigned* bar = (unsigned*)(w + 10878976);

    // zero h0,h1 and the barrier counter (fresh every call -> deterministic replay)
    hipMemsetAsync(h0T, 0, 2 * 65536 * sizeof(float), stream);
    hipMemsetAsync(bar, 0, 64, stream);

    norm_rows<<<V_, 256, 0, stream>>>(emb, nemb, V_, E_);
    norm_rows<<<10, 256, 0, stream>>>(lemb, nlang, 10, LD_);
    build_xsT<<<(D0_ * BT_ + 255) / 256, 256, 0, stream>>>(inp, langs, nemb, nlang, xsT);
    // Xg0T[n][m] = sum_k Wg0[k][n]*xsT[k][m] + bg0[n]  (x-part rows 0..199)
    gemm_at_bias<<<dim3(80, 16), 256, 0, stream>>>(Wg0, xsT, bg0, Xg0T, 1024);
    gemm_at_bias<<<dim3(80, 8), 256, 0, stream>>>(Wc0, xsT, bc0, Xc0T, 512);
    rnn_persistent<<<NBLK_, 256, 0, stream>>>(Xg0T, Xc0T, Wg0, Wc0, Wg1, bg1, Wc1, bc1,
                                              h0T, h1T, rh0T, u0T, rh1T, u1T, h1oT, bar);
    lse_gemm<<<dim3(125, 79), 256, 0, stream>>>(h1oT, sw, sb, tgt, ztb, parts);
    final_nll<<<40, 128, 0, stream>>>(parts, ztb, bsum);
    final_sum<<<1, 64, 0, stream>>>(bsum, out);
}

// Round 3
// 4759.833 us; speedup vs baseline: 3.2306x; 2.9635x over previous
//
#include <hip/hip_runtime.h>
#include <hip/hip_bf16.h>
#include <math.h>

// Problem constants
#define V_    8000
#define E_    150
#define LD_   50
#define H_    512
#define B_    100
#define T_    50
#define D0_   200   // E_+LD_
#define BT_   5000  // B_*T_
#define NV_   8000

typedef __attribute__((ext_vector_type(8))) short short8v;
typedef __attribute__((ext_vector_type(4))) float f32x4;

__device__ __forceinline__ float sigmoidf_(float x) { return 1.0f / (1.0f + expf(-x)); }
__device__ __forceinline__ unsigned short f2b(float x) {
    __hip_bfloat16 b = __float2bfloat16(x);
    return *(unsigned short*)&b;
}

// ---------------- row L2-normalize
__global__ __launch_bounds__(256) void norm_rows(const float* __restrict__ in,
                                                 float* __restrict__ out, int R, int C) {
    int row = blockIdx.x;
    if (row >= R) return;
    int tid = threadIdx.x;
    float v = (tid < C) ? in[(size_t)row * C + tid] : 0.f;
    __shared__ float red[256];
    red[tid] = v * v;
    __syncthreads();
    for (int s = 128; s > 0; s >>= 1) {
        if (tid < s) red[tid] += red[tid + s];
        __syncthreads();
    }
    float scale = rsqrtf(fmaxf(red[0], 1e-12f));
    if (tid < C) out[(size_t)row * C + tid] = v * scale;
}

// ---------------- build xs [m=t*100+b][D0] row-major
__global__ void build_xs(const int* __restrict__ inp, const int* __restrict__ langs,
                         const float* __restrict__ nemb, const float* __restrict__ nlang,
                         float* __restrict__ xs) {
    int idx = blockIdx.x * 256 + threadIdx.x;
    if (idx >= T_ * B_ * D0_) return;
    int t = idx / (B_ * D0_);
    int rem = idx % (B_ * D0_);
    int b = rem / D0_;
    int e = rem % D0_;
    float v;
    if (e < E_) v = nemb[(size_t)inp[b * T_ + t] * E_ + e];
    else        v = nlang[(size_t)langs[b] * LD_ + (e - E_)];
    xs[idx] = v;
}

// ---------------- fp32 tiled GEMM + bias: C[M,N] = A[M,K]@B[K,N](ldb) + bias
__global__ __launch_bounds__(256) void gemm_bias(const float* __restrict__ A,
                                                 const float* __restrict__ Bm,
                                                 const float* __restrict__ bias,
                                                 float* __restrict__ C,
                                                 int M, int N, int K, int ldb) {
    __shared__ __align__(16) float As[16][64];
    __shared__ __align__(16) float Bs[16][64];
    const int tid = threadIdx.x;
    const int tx = tid & 15, ty = tid >> 4;
    const int mBase = blockIdx.y * 64, nBase = blockIdx.x * 64;
    float acc[4][4] = {};
    for (int k0 = 0; k0 < K; k0 += 16) {
        int e = tid * 4;
#pragma unroll
        for (int q = 0; q < 4; ++q) {
            int ee = e + q;
            int r = ee >> 4, kk = ee & 15;
            int gr = mBase + r, gk = k0 + kk;
            As[kk][r] = (gr < M && gk < K) ? A[(size_t)gr * K + gk] : 0.f;
        }
        int bk = tid >> 4, bn = (tid & 15) * 4;
        int gk = k0 + bk;
        float4 bv = make_float4(0.f, 0.f, 0.f, 0.f);
        if (gk < K) bv = *(const float4*)(Bm + (size_t)gk * ldb + nBase + bn);
        *(float4*)&Bs[bk][bn] = bv;
        __syncthreads();
#pragma unroll
        for (int kk = 0; kk < 16; ++kk) {
            const float4 a4 = *(const float4*)&As[kk][ty * 4];
            const float4 b4 = *(const float4*)&Bs[kk][tx * 4];
            float a[4] = {a4.x, a4.y, a4.z, a4.w};
            float b[4] = {b4.x, b4.y, b4.z, b4.w};
#pragma unroll
            for (int i = 0; i < 4; ++i)
#pragma unroll
                for (int j = 0; j < 4; ++j) acc[i][j] += a[i] * b[j];
        }
        __syncthreads();
    }
#pragma unroll
    for (int i = 0; i < 4; ++i) {
        int gr = mBase + ty * 4 + i;
        if (gr < M) {
#pragma unroll
            for (int j = 0; j < 4; ++j) {
                int gc = nBase + tx * 4 + j;
                if (gc < N) C[(size_t)gr * N + gc] = acc[i][j] + bias[gc];
            }
        }
    }
}

// ---------------- pack fp32 weight [K][ldw] (rows k0off..) into bf16 MFMA B-frag layout:
// dst[((kt*NT + nt)*64 + lane)*8 + j] = bf16(W[k0off + kt*32 + (lane>>4)*8 + j][nt*16 + (lane&15)])
__global__ __launch_bounds__(256) void pack_frags(const float* __restrict__ W, int ldw,
                                                  int k0off, int KT, int NT,
                                                  unsigned short* __restrict__ dst) {
    int idx = blockIdx.x * 256 + threadIdx.x;
    if (idx >= KT * NT * 64) return;
    int lane = idx & 63;
    int tile = idx >> 6;
    int nt = tile % NT, kt = tile / NT;
    int n = nt * 16 + (lane & 15);
    int kb = k0off + kt * 32 + (lane >> 4) * 8;
    unsigned short o[8];
#pragma unroll
    for (int j = 0; j < 8; ++j) o[j] = f2b(W[(size_t)(kb + j) * ldw + n]);
    *(uint4*)(dst + (size_t)idx * 8) = *(const uint4*)o;
}

// ---------------- MFMA recurrence phase: acc[nt] += A(h, 16x32 tiles) x B(W-frags)
// K = KT*32; A k-tiles 0..15 from a0, 16..31 from a1. aoff = (lane&15)*520 + (lane>>4)*8.
template<int KT, int NTW>
__device__ __forceinline__ void mm_phase(const unsigned short* __restrict__ Wf, int NT,
                                         const unsigned short* a0, const unsigned short* a1,
                                         int w, int lane, int aoff, f32x4* acc) {
#pragma unroll 2
    for (int kt = 0; kt < KT; ++kt) {
        const unsigned short* src = (KT > 16 && kt >= 16) ? a1 : a0;
        int ktl = (KT > 16 && kt >= 16) ? kt - 16 : kt;
        short8v af = *(const short8v*)(src + aoff + ktl * 32);
        const unsigned short* wp = Wf + ((size_t)(kt * NT + w * NTW) * 64 + lane) * 8;
#pragma unroll
        for (int nt = 0; nt < NTW; ++nt) {
            short8v bf = *(const short8v*)(wp + (size_t)nt * 512);
            acc[nt] = __builtin_amdgcn_mfma_f32_16x16x32_bf16(af, bf, acc[nt], 0, 0, 0);
        }
    }
}

// ---------------- barrier-free recurrence: 50 blocks x 2 batch rows, 512 threads (8 waves)
// Weights streamed as pre-packed bf16 fragments; h state in LDS (fp32 master + bf16 mirror).
__global__ __launch_bounds__(512) void rnn_mfma(
    const float* __restrict__ Xg0, const float* __restrict__ Xc0,
    const unsigned short* __restrict__ Wg0f, const unsigned short* __restrict__ Wc0f,
    const unsigned short* __restrict__ Wg1f, const unsigned short* __restrict__ Wc1f,
    const float* __restrict__ bg1, const float* __restrict__ bc1,
    float* __restrict__ h1o) {
    __shared__ __align__(16) unsigned short h0b[16 * 520];
    __shared__ __align__(16) unsigned short h1b[16 * 520];
    __shared__ __align__(16) unsigned short rh0b[16 * 520];
    __shared__ __align__(16) unsigned short rh1b[16 * 520];
    __shared__ float h0f[2 * 512], h1f[2 * 512], u0f[2 * 512], u1f[2 * 512];
    const int tid = threadIdx.x;
    const int w = tid >> 6, lane = tid & 63;
    const int arow = lane & 15;
    const int aoff = arow * 520 + (lane >> 4) * 8;
    const int rb = blockIdx.x * 2;

    for (int i = tid; i < 16 * 520; i += 512) { h0b[i] = 0; h1b[i] = 0; rh0b[i] = 0; rh1b[i] = 0; }
    for (int i = tid; i < 2 * 512; i += 512) { h0f[i] = 0.f; h1f[i] = 0.f; }
    // hoist layer-1 biases (fixed cols per lane)
    float bg1v[8], bc1v[4];
#pragma unroll
    for (int nt = 0; nt < 8; ++nt) bg1v[nt] = bg1[(w * 8 + nt) * 16 + arow];
#pragma unroll
    for (int nt = 0; nt < 4; ++nt) bc1v[nt] = bc1[(w * 4 + nt) * 16 + arow];
    __syncthreads();

    for (int t = 0; t < T_; ++t) {
        const int m0 = t * 100 + rb, m1 = m0 + 1;
        {   // phase A: gates0 = sigmoid(Xg0 + h0 @ Wg0h)  [N=1024, K=512]
            f32x4 acc[8];
#pragma unroll
            for (int nt = 0; nt < 8; ++nt) acc[nt] = (f32x4){0.f, 0.f, 0.f, 0.f};
            mm_phase<16, 8>(Wg0f, 64, h0b, h0b, w, lane, aoff, acc);
            if (lane < 16) {
#pragma unroll
                for (int nt = 0; nt < 8; ++nt) {
                    int col = (w * 8 + nt) * 16 + arow;
                    float s0 = sigmoidf_(acc[nt][0] + Xg0[(size_t)m0 * 1024 + col]);
                    float s1 = sigmoidf_(acc[nt][1] + Xg0[(size_t)m1 * 1024 + col]);
                    if (col < 512) {
                        rh0b[col]       = f2b(s0 * h0f[col]);
                        rh0b[520 + col] = f2b(s1 * h0f[512 + col]);
                    } else {
                        u0f[col - 512] = s0;
                        u0f[col]       = s1;
                    }
                }
            }
        }
        __syncthreads();
        {   // phase B: h0 = u*h0 + (1-u)*tanh(Xc0 + rh0 @ Wc0h)  [N=512, K=512]
            f32x4 acc[4];
#pragma unroll
            for (int nt = 0; nt < 4; ++nt) acc[nt] = (f32x4){0.f, 0.f, 0.f, 0.f};
            mm_phase<16, 4>(Wc0f, 32, rh0b, rh0b, w, lane, aoff, acc);
            if (lane < 16) {
#pragma unroll
                for (int nt = 0; nt < 4; ++nt) {
                    int col = (w * 4 + nt) * 16 + arow;
                    float c0 = tanhf(acc[nt][0] + Xc0[(size_t)m0 * 512 + col]);
                    float c1 = tanhf(acc[nt][1] + Xc0[(size_t)m1 * 512 + col]);
                    float uA = u0f[col], uB = u0f[512 + col];
                    float hA = uA * h0f[col] + (1.f - uA) * c0;
                    float hB = uB * h0f[512 + col] + (1.f - uB) * c1;
                    h0f[col] = hA; h0f[512 + col] = hB;
                    h0b[col] = f2b(hA); h0b[520 + col] = f2b(hB);
                }
            }
        }
        __syncthreads();
        {   // phase C: gates1 = sigmoid(bg1 + [h0,h1] @ Wg1)  [N=1024, K=1024]
            f32x4 acc[8];
#pragma unroll
            for (int nt = 0; nt < 8; ++nt) acc[nt] = (f32x4){0.f, 0.f, 0.f, 0.f};
            mm_phase<32, 8>(Wg1f, 64, h0b, h1b, w, lane, aoff, acc);
            if (lane < 16) {
#pragma unroll
                for (int nt = 0; nt < 8; ++nt) {
                    int col = (w * 8 + nt) * 16 + arow;
                    float s0 = sigmoidf_(acc[nt][0] + bg1v[nt]);
                    float s1 = sigmoidf_(acc[nt][1] + bg1v[nt]);
                    if (col < 512) {
                        rh1b[col]       = f2b(s0 * h1f[col]);
                        rh1b[520 + col] = f2b(s1 * h1f[512 + col]);
                    } else {
                        u1f[col - 512] = s0;
                        u1f[col]       = s1;
                    }
                }
            }
        }
        __syncthreads();
        {   // phase D: h1 = u1*h1 + (1-u1)*tanh(bc1 + [h0, rh1] @ Wc1)  [N=512, K=1024]
            f32x4 acc[4];
#pragma unroll
            for (int nt = 0; nt < 4; ++nt) acc[nt] = (f32x4){0.f, 0.f, 0.f, 0.f};
            mm_phase<32, 4>(Wc1f, 32, h0b, rh1b, w, lane, aoff, acc);
            if (lane < 16) {
#pragma unroll
                for (int nt = 0; nt < 4; ++nt) {
                    int col = (w * 4 + nt) * 16 + arow;
                    float c0 = tanhf(acc[nt][0] + bc1v[nt]);
                    float c1 = tanhf(acc[nt][1] + bc1v[nt]);
                    float uA = u1f[col], uB = u1f[512 + col];
                    float hA = uA * h1f[col] + (1.f - uA) * c0;
                    float hB = uB * h1f[512 + col] + (1.f - uB) * c1;
                    h1f[col] = hA; h1f[512 + col] = hB;
                    h1b[col] = f2b(hA); h1b[520 + col] = f2b(hB);
                    h1o[(size_t)m0 * 512 + col] = hA;
                    h1o[(size_t)m1 * 512 + col] = hB;
                }
            }
        }
        __syncthreads();
    }
}

// ---------------- fused softmax GEMM + per-tile LSE partials + target-logit pick
// A = h1o [BT][512] row-major, B = sw [512][8000]
__global__ __launch_bounds__(256) void lse_gemm(const float* __restrict__ A,
                                                const float* __restrict__ Bw,
                                                const float* __restrict__ bias,
                                                const int* __restrict__ tgt,
                                                float* __restrict__ zt,
                                                float* __restrict__ parts, int M) {
    __shared__ __align__(16) float As[16][64];
    __shared__ __align__(16) float Bs[16][64];
    __shared__ float red[64][17];
    __shared__ float rowm[64];
    const int tid = threadIdx.x;
    const int tx = tid & 15, ty = tid >> 4;
    const int mBase = blockIdx.y * 64, nBase = blockIdx.x * 64;
    float acc[4][4] = {};
    for (int k0 = 0; k0 < 512; k0 += 16) {
        int r = tid >> 2;
        int ak = (tid & 3) * 4;
        float4 av = make_float4(0.f, 0.f, 0.f, 0.f);
        if (mBase + r < M) av = *(const float4*)(A + (size_t)(mBase + r) * 512 + k0 + ak);
        As[ak][r] = av.x; As[ak + 1][r] = av.y; As[ak + 2][r] = av.z; As[ak + 3][r] = av.w;
        int bk = tid >> 4, bn = (tid & 15) * 4;
        float4 bv = *(const float4*)(Bw + (size_t)(k0 + bk) * NV_ + nBase + bn);
        *(float4*)&Bs[bk][bn] = bv;
        __syncthreads();
#pragma unroll
        for (int kk = 0; kk < 16; ++kk) {
            const float4 a4 = *(const float4*)&As[kk][ty * 4];
            const float4 b4 = *(const float4*)&Bs[kk][tx * 4];
            float a[4] = {a4.x, a4.y, a4.z, a4.w};
            float b[4] = {b4.x, b4.y, b4.z, b4.w};
#pragma unroll
            for (int i = 0; i < 4; ++i)
#pragma unroll
                for (int j = 0; j < 4; ++j) acc[i][j] += a[i] * b[j];
        }
        __syncthreads();
    }
#pragma unroll
    for (int j = 0; j < 4; ++j) {
        float bb = bias[nBase + tx * 4 + j];
#pragma unroll
        for (int i = 0; i < 4; ++i) acc[i][j] += bb;
    }
    // target-logit pick: row m = t*100+b pairs with tgt[b*50+t] = tgt[(m%100)*50 + m/100]
#pragma unroll
    for (int i = 0; i < 4; ++i) {
        int gr = mBase + ty * 4 + i;
        if (gr < M) {
            int tg = tgt[(gr % 100) * 50 + gr / 100];
            int lj = tg - nBase - tx * 4;
            if (lj == 0) zt[gr] = acc[i][0];
            else if (lj == 1) zt[gr] = acc[i][1];
            else if (lj == 2) zt[gr] = acc[i][2];
            else if (lj == 3) zt[gr] = acc[i][3];
        }
    }
#pragma unroll
    for (int i = 0; i < 4; ++i) {
        float lm = fmaxf(fmaxf(acc[i][0], acc[i][1]), fmaxf(acc[i][2], acc[i][3]));
        red[ty * 4 + i][tx] = lm;
    }
    __syncthreads();
    if (tid < 64) {
        float m = red[tid][0];
#pragma unroll
        for (int c = 1; c < 16; ++c) m = fmaxf(m, red[tid][c]);
        rowm[tid] = m;
    }
    __syncthreads();
#pragma unroll
    for (int i = 0; i < 4; ++i) {
        float m = rowm[ty * 4 + i];
        float ls = expf(acc[i][0] - m) + expf(acc[i][1] - m) + expf(acc[i][2] - m) + expf(acc[i][3] - m);
        red[ty * 4 + i][tx] = ls;
    }
    __syncthreads();
    if (tid < 64) {
        float s = 0.f;
#pragma unroll
        for (int c = 0; c < 16; ++c) s += red[tid][c];
        int gr = mBase + tid;
        if (gr < M) {
            parts[(size_t)gr * 250 + blockIdx.x * 2 + 0] = rowm[tid];
            parts[(size_t)gr * 250 + blockIdx.x * 2 + 1] = s;
        }
    }
}

// ---------------- merge partials -> NLL -> block sums
__global__ __launch_bounds__(128) void final_nll(const float* __restrict__ parts,
                                                 const float* __restrict__ zt,
                                                 float* __restrict__ bsum) {
    int i = blockIdx.x * 128 + threadIdx.x;
    float nll = 0.f;
    if (i < BT_) {
        const float* p = parts + (size_t)i * 250;
        float M = p[0];
        for (int j = 1; j < 125; ++j) M = fmaxf(M, p[2 * j]);
        float S = 0.f;
        for (int j = 0; j < 125; ++j) S += p[2 * j + 1] * expf(p[2 * j] - M);
        nll = M + logf(S) - zt[i];
    }
    __shared__ float red[128];
    red[threadIdx.x] = nll;
    __syncthreads();
    for (int s = 64; s > 0; s >>= 1) {
        if (threadIdx.x < s) red[threadIdx.x] += red[threadIdx.x + s];
        __syncthreads();
    }
    if (threadIdx.x == 0) bsum[blockIdx.x] = red[0];
}

__global__ __launch_bounds__(64) void final_sum(const float* __restrict__ bsum,
                                                float* __restrict__ out) {
    int tid = threadIdx.x;
    float v = (tid < 40) ? bsum[tid] : 0.f;
    for (int off = 32; off > 0; off >>= 1) v += __shfl_down(v, off);
    if (tid == 0) out[0] = v / 5000.0f;
}

extern "C" void kernel_launch(void* const* d_in, const int* in_sizes, int n_in,
                              void* d_out, int out_size, void* d_ws, size_t ws_size,
                              hipStream_t stream) {
    const int*   inp   = (const int*)d_in[0];
    const int*   langs = (const int*)d_in[1];
    const int*   tgt   = (const int*)d_in[2];
    const float* emb   = (const float*)d_in[3];
    const float* lemb  = (const float*)d_in[4];
    const float* Wg0   = (const float*)d_in[5];
    const float* bg0   = (const float*)d_in[6];
    const float* Wc0   = (const float*)d_in[7];
    const float* bc0   = (const float*)d_in[8];
    const float* Wg1   = (const float*)d_in[9];
    const float* bg1   = (const float*)d_in[10];
    const float* Wc1   = (const float*)d_in[11];
    const float* bc1   = (const float*)d_in[12];
    const float* sw    = (const float*)d_in[13];
    const float* sb    = (const float*)d_in[14];
    float* out = (float*)d_out;

    // workspace layout (floats), total 12,440,512 floats = 49.76 MB
    float* w = (float*)d_ws;
    // region A [0 .. 1,200,000): nemb, later aliased by packed weight frags (1,179,648 fl)
    float* nemb  = w;
    unsigned short* Wg0f = (unsigned short*)w;                 //   524,288 u16
    unsigned short* Wg1f = Wg0f + 524288;                      // 1,048,576 u16
    unsigned short* Wc0f = Wg1f + 1048576;                     //   262,144 u16
    unsigned short* Wc1f = Wc0f + 262144;                      //   524,288 u16 (ends 2,359,296 u16)
    float* nlang = w + 1200000;             // 512
    float* xs    = w + 1200512;             // 1,000,000 (dead after gemms)
    float* Xg0   = w + 2200512;             // 5,120,000, later aliased by parts/zt/bsum
    float* parts = w + 2200512;             // 1,250,000
    float* ztb   = w + 2200512 + 1250000;   // 5,000
    float* bsum  = w + 2200512 + 1255000;   // 64
    float* Xc0   = w + 7320512;             // 2,560,000
    float* h1o   = w + 9880512;             // 2,560,000 (ends 12,440,512)

    norm_rows<<<V_, 256, 0, stream>>>(emb, nemb, V_, E_);
    norm_rows<<<10, 256, 0, stream>>>(lemb, nlang, 10, LD_);
    build_xs<<<(T_ * B_ * D0_ + 255) / 256, 256, 0, stream>>>(inp, langs, nemb, nlang, xs);
    // pack weights into bf16 B-fragment layout (overwrites nemb region; after build_xs)
    pack_frags<<<256, 256, 0, stream>>>(Wg0, 1024, D0_, 16, 64, Wg0f);   // h-part rows 200..711
    pack_frags<<<512, 256, 0, stream>>>(Wg1, 1024, 0,   32, 64, Wg1f);
    pack_frags<<<128, 256, 0, stream>>>(Wc0,  512, D0_, 16, 32, Wc0f);
    pack_frags<<<256, 256, 0, stream>>>(Wc1,  512, 0,   32, 32, Wc1f);
    // input-side projections (x-part of layer-0 GRU), row-major [m][N]
    gemm_bias<<<dim3(16, 79), 256, 0, stream>>>(xs, Wg0, bg0, Xg0, BT_, 1024, D0_, 1024);
    gemm_bias<<<dim3(8, 79), 256, 0, stream>>>(xs, Wc0, bc0, Xc0, BT_, 512, D0_, 512);
    // barrier-free MFMA recurrence
    rnn_mfma<<<50, 512, 0, stream>>>(Xg0, Xc0, Wg0f, Wc0f, Wg1f, Wc1f, bg1, bc1, h1o);
    // fused softmax GEMM + LSE partials + target pick
    lse_gemm<<<dim3(125, 79), 256, 0, stream>>>(h1o, sw, sb, tgt, ztb, parts, BT_);
    final_nll<<<40, 128, 0, stream>>>(parts, ztb, bsum);
    final_sum<<<1, 64, 0, stream>>>(bsum, out);
}